// Round 1
// baseline (257.583 us; speedup 1.0000x reference)
//
#include <hip/hip_runtime.h>
#include <math.h>

#define DEVFN __device__ __forceinline__

constexpr int Bc = 2, Lc = 256, DMc = 256, Hc = 8, NKc = 4, Tc = 4, DHc = 32;
constexpr float LOG2E = 1.4426950408889634f;
constexpr float RSQRT_DH = 0.17677669529663687f; // 1/sqrt(32)

// ---------------------------------------------------------------------------
// Pack gaussian params into wave-uniform-friendly layout:
//   out[h*512 + t*128 + d*4 + k] = {mu, -log2e/(2*sigma^2), w/DH, 0}
// so inner loops do: acc += q.z * exp2f(d*d*q.y) with d = tr - q.x
// ---------------------------------------------------------------------------
__global__ void k_pack(const float* __restrict__ mu, const float* __restrict__ sg,
                       const float* __restrict__ w, float4* __restrict__ out) {
    int p = blockIdx.x * 256 + threadIdx.x;    // [0, 4096)
    int h = p >> 9;
    int r = p & 511;
    int t = r >> 7;
    int dk = r & 127;
    int d = dk >> 2, k = dk & 3;
    int src = ((h * DHc + d) * Tc + t) * NKc + k;
    float s = sg[src];
    float negc = -LOG2E / (2.0f * s * s);
    out[p] = make_float4(mu[src], negc, w[src] * (1.0f / (float)DHc), 0.0f);
}

// ---------------------------------------------------------------------------
// g_abs[b,h,i] = sum over 512 packed params of w*exp(...) at tr = t[b,i,tg]
// grid (B*H, L/64), block 256 = 64 i x 4 t-groups (params wave-uniform).
// ---------------------------------------------------------------------------
__global__ void k_gabs(const float* __restrict__ tarr, const float4* __restrict__ pabs,
                       float* __restrict__ gabs) {
    int b = blockIdx.x / Hc, h = blockIdx.x % Hc;
    int lane = threadIdx.x & 63;
    int tg = threadIdx.x >> 6;
    int i = blockIdx.y * 64 + lane;
    float tv = tarr[(b * Lc + i) * Tc + tg];
    const float4* pp = pabs + (h * Tc + tg) * 128;
    float a0 = 0.f, a1 = 0.f;
    #pragma unroll 4
    for (int m = 0; m < 128; m += 2) {
        float4 q0 = pp[m], q1 = pp[m + 1];
        float d0 = tv - q0.x; a0 += q0.z * exp2f(d0 * d0 * q0.y);
        float d1 = tv - q1.x; a1 += q1.z * exp2f(d1 * d1 * q1.y);
    }
    __shared__ float red[4][64];
    red[tg][lane] = a0 + a1;
    __syncthreads();
    if (threadIdx.x < 64)
        gabs[(b * Hc + h) * Lc + i] = red[0][lane] + red[1][lane] + red[2][lane] + red[3][lane];
}

// ---------------------------------------------------------------------------
// g_rel[b,h,i,j] for all h; exploits |t_i-t_j| symmetry: only upper-triangle
// 16x16 tiles computed; off-diagonal tiles mirror-written via LDS transpose.
// grid (136 tile-pairs, B, 2 h-halves), block 256 = 16x16 (i,j).
// Params are wave-uniform -> s_load_dwordx4; inner loop = 4 VALU + 1 exp/eval.
// ---------------------------------------------------------------------------
__global__ void __launch_bounds__(256) k_grel(const float* __restrict__ tarr,
                                              const float4* __restrict__ prel,
                                              float* __restrict__ grel) {
    int p = blockIdx.x;
    int b = blockIdx.y;
    int hz = blockIdx.z;
    constexpr int NT = Lc / 16;
    int ti = 0;
    for (;; ++ti) { int cnt = NT - ti; if (p < cnt) break; p -= cnt; }
    int tj = ti + p;
    int di = threadIdx.x >> 4, dj = threadIdx.x & 15;
    int i = ti * 16 + di, j = tj * 16 + dj;
    float4 t_i = *(const float4*)(tarr + (b * Lc + i) * Tc);
    float4 t_j = *(const float4*)(tarr + (b * Lc + j) * Tc);
    float tr0 = fabsf(t_i.x - t_j.x), tr1 = fabsf(t_i.y - t_j.y);
    float tr2 = fabsf(t_i.z - t_j.z), tr3 = fabsf(t_i.w - t_j.w);
    __shared__ float lt[16][17];
    for (int hh = 0; hh < 4; ++hh) {
        int h = hz * 4 + hh;
        const float4* base = prel + h * 512;
        float a0 = 0.f, a1 = 0.f, a2 = 0.f, a3 = 0.f;
        #pragma unroll 4
        for (int m = 0; m < 128; ++m) {
            float4 q0 = base[m];
            float4 q1 = base[128 + m];
            float4 q2 = base[256 + m];
            float4 q3 = base[384 + m];
            float d0 = tr0 - q0.x; a0 += q0.z * exp2f(d0 * d0 * q0.y);
            float d1 = tr1 - q1.x; a1 += q1.z * exp2f(d1 * d1 * q1.y);
            float d2 = tr2 - q2.x; a2 += q2.z * exp2f(d2 * d2 * q2.y);
            float d3 = tr3 - q3.x; a3 += q3.z * exp2f(d3 * d3 * q3.y);
        }
        float g = (a0 + a1) + (a2 + a3);
        float* gb = grel + (size_t)(b * Hc + h) * (Lc * Lc);
        gb[i * Lc + j] = g;
        if (ti != tj) {
            __syncthreads();
            lt[di][dj] = g;
            __syncthreads();
            // mirror tile: row (tj*16+di), col (ti*16+dj) <- tile[dj][di]
            gb[(tj * 16 + di) * Lc + (ti * 16 + dj)] = lt[dj][di];
        }
    }
}

// ---------------------------------------------------------------------------
// fp32 GEMM  C[M,N] = A[M,K] @ W[N,K]^T (+bias), LDS tiles stored [k][m].
// blockIdx.z selects among 3 weight/output pairs (fused QKV).
// ---------------------------------------------------------------------------
template<int R, int PER>
DEVFN void stage_tile(const float* __restrict__ src, int ld, int row0, int k0,
                      float* __restrict__ dst, int tid) {
    int row = tid / (16 / PER);
    int cb = (tid % (16 / PER)) * PER;
    const float* g = src + (size_t)(row0 + row) * ld + k0 + cb;
    float v[PER];
    #pragma unroll
    for (int u = 0; u < PER; ++u) v[u] = g[u];
    #pragma unroll
    for (int u = 0; u < PER; ++u) dst[(cb + u) * R + row] = v[u];
}

template<int BM, int BN, int TM, int TN>
__global__ void __launch_bounds__(256) k_gemm_nt(
    const float* __restrict__ A,
    const float* __restrict__ W0, const float* __restrict__ W1, const float* __restrict__ W2,
    float* __restrict__ C0, float* __restrict__ C1, float* __restrict__ C2,
    const float* __restrict__ bias, int M, int N, int K)
{
    const float* W = (blockIdx.z == 0) ? W0 : (blockIdx.z == 1 ? W1 : W2);
    float* C = (blockIdx.z == 0) ? C0 : (blockIdx.z == 1 ? C1 : C2);
    __shared__ float As[16 * BM];
    __shared__ float Ws[16 * BN];
    int tid = threadIdx.x;
    int tx = tid % (BN / TN);
    int ty = tid / (BN / TN);
    int m0 = blockIdx.x * BM, n0 = blockIdx.y * BN;
    float acc[TM][TN] = {};
    for (int k0 = 0; k0 < K; k0 += 16) {
        stage_tile<BM, BM * 16 / 256>(A, K, m0, k0, As, tid);
        stage_tile<BN, BN * 16 / 256>(W, K, n0, k0, Ws, tid);
        __syncthreads();
        #pragma unroll
        for (int k = 0; k < 16; ++k) {
            float a[TM], w[TN];
            #pragma unroll
            for (int u = 0; u < TM; ++u) a[u] = As[k * BM + ty * TM + u];
            #pragma unroll
            for (int v = 0; v < TN; ++v) w[v] = Ws[k * BN + tx * TN + v];
            #pragma unroll
            for (int u = 0; u < TM; ++u)
                #pragma unroll
                for (int v = 0; v < TN; ++v)
                    acc[u][v] += a[u] * w[v];
        }
        __syncthreads();
    }
    #pragma unroll
    for (int u = 0; u < TM; ++u) {
        int m = m0 + ty * TM + u;
        #pragma unroll
        for (int v = 0; v < TN; ++v) {
            float o = acc[u][v];
            if (bias) o += bias[n0 + tx * TN + v];
            C[(size_t)m * N + n0 + tx * TN + v] = o;
        }
    }
}

// ---------------------------------------------------------------------------
// Fused attention: per (b, h, 16-row i-tile):
//   S = QK^T/sqrt(dh), P = XX^T (4x2 outer-product frags, j in 2 halves of 128,
//   K/X staged transposed [k][j] in LDS), logits = S*(P*(2*alpha*g_i +
//   beta*g_rel) + gamma), register wave-wide softmax, then PV from LDS.
// LDS 53.5 KB: Kt/Xt halves reused for V after phase 1.
// ---------------------------------------------------------------------------
__global__ void __launch_bounds__(256) k_attn(
    const float* __restrict__ Q, const float* __restrict__ K, const float* __restrict__ V,
    const float* __restrict__ x, const float* __restrict__ gabs, const float* __restrict__ grel,
    const float* __restrict__ alpha, const float* __restrict__ beta, const float* __restrict__ gamma,
    float* __restrict__ attn_out)
{
    int it = blockIdx.x, h = blockIdx.y, b = blockIdx.z;
    int i0 = it * 16;
    int tid = threadIdx.x;

    __shared__ float sm[13376];
    float* sKt = sm;            // [32][128] half-j, pitch 128
    float* sXt = sm + 4096;     // [32][128]
    float* sV  = sm;            // [256][32]  (reuses Kt+Xt after phase 1)
    float* sQ  = sm + 8192;     // [32][16]
    float* sXi = sm + 8704;     // [32][16]
    float* sL  = sm + 9216;     // [16][260]

    int ig = tid >> 6;          // wave id == i-frag group (4 rows each)
    int jg = tid & 63;

    // stage Q rows / X i-rows transposed [k][i] (pitch 16)
    {
        int tt = tid & 127;
        int r = tt >> 3;
        int c4 = (tt & 7) * 4;
        const float* src = (tid < 128)
            ? (Q + ((size_t)(b * Lc + i0 + r) * DMc + h * DHc + c4))
            : (x + ((size_t)(b * Lc + i0 + r) * DMc + h * DHc + c4));
        float* dst = (tid < 128) ? sQ : sXi;
        float4 v = *(const float4*)src;
        dst[(c4 + 0) * 16 + r] = v.x;
        dst[(c4 + 1) * 16 + r] = v.y;
        dst[(c4 + 2) * 16 + r] = v.z;
        dst[(c4 + 3) * 16 + r] = v.w;
    }

    float la = alpha[h], lb = beta[h], lg = gamma[h];
    float ca[4];
    #pragma unroll
    for (int u = 0; u < 4; ++u)
        ca[u] = 2.0f * la * gabs[(b * Hc + h) * Lc + i0 + ig * 4 + u];
    const float* grow = grel + (size_t)(b * Hc + h) * (Lc * Lc);

    float lo[4][4];   // [ii][q], q -> j = {2jg, 2jg+1, 128+2jg, 129+2jg}

    #pragma unroll
    for (int half = 0; half < 2; ++half) {
        int jb = half * 128;
        __syncthreads();   // protect prev half's Kt/Xt reads
        #pragma unroll
        for (int u = 0; u < 4; ++u) {
            int j = (tid >> 3) + u * 32;
            int d4 = (tid & 7) * 4;
            float4 kv = *(const float4*)(K + ((size_t)(b * Lc + jb + j) * DMc + h * DHc + d4));
            float4 xv = *(const float4*)(x + ((size_t)(b * Lc + jb + j) * DMc + h * DHc + d4));
            sKt[(d4 + 0) * 128 + j] = kv.x;
            sKt[(d4 + 1) * 128 + j] = kv.y;
            sKt[(d4 + 2) * 128 + j] = kv.z;
            sKt[(d4 + 3) * 128 + j] = kv.w;
            sXt[(d4 + 0) * 128 + j] = xv.x;
            sXt[(d4 + 1) * 128 + j] = xv.y;
            sXt[(d4 + 2) * 128 + j] = xv.z;
            sXt[(d4 + 3) * 128 + j] = xv.w;
        }
        __syncthreads();

        float accS[4][2] = {}, accP[4][2] = {};
        #pragma unroll
        for (int k = 0; k < 32; ++k) {
            float4 aq = *(const float4*)(sQ + k * 16 + ig * 4);
            float4 ax = *(const float4*)(sXi + k * 16 + ig * 4);
            float2 bk = *(const float2*)(sKt + k * 128 + jg * 2);
            float2 bx = *(const float2*)(sXt + k * 128 + jg * 2);
            accS[0][0] += aq.x * bk.x; accS[0][1] += aq.x * bk.y;
            accS[1][0] += aq.y * bk.x; accS[1][1] += aq.y * bk.y;
            accS[2][0] += aq.z * bk.x; accS[2][1] += aq.z * bk.y;
            accS[3][0] += aq.w * bk.x; accS[3][1] += aq.w * bk.y;
            accP[0][0] += ax.x * bx.x; accP[0][1] += ax.x * bx.y;
            accP[1][0] += ax.y * bx.x; accP[1][1] += ax.y * bx.y;
            accP[2][0] += ax.z * bx.x; accP[2][1] += ax.z * bx.y;
            accP[3][0] += ax.w * bx.x; accP[3][1] += ax.w * bx.y;
        }
        #pragma unroll
        for (int u = 0; u < 4; ++u) {
            float2 gr = *(const float2*)(grow + (size_t)(i0 + ig * 4 + u) * Lc + jb + jg * 2);
            float t0 = fmaf(lb, gr.x, ca[u]);
            float t1 = fmaf(lb, gr.y, ca[u]);
            float A0 = fmaf(accP[u][0], t0, lg);
            float A1 = fmaf(accP[u][1], t1, lg);
            lo[u][half * 2 + 0] = accS[u][0] * RSQRT_DH * A0;
            lo[u][half * 2 + 1] = accS[u][1] * RSQRT_DH * A1;
        }
    }

    // register softmax: each row (ig*4+u) fully distributed across this wave
    float sum[4];
    #pragma unroll
    for (int u = 0; u < 4; ++u) {
        float m = fmaxf(fmaxf(lo[u][0], lo[u][1]), fmaxf(lo[u][2], lo[u][3]));
        #pragma unroll
        for (int s = 1; s < 64; s <<= 1)
            m = fmaxf(m, __shfl_xor(m, s, 64));
        float e0 = exp2f((lo[u][0] - m) * LOG2E);
        float e1 = exp2f((lo[u][1] - m) * LOG2E);
        float e2 = exp2f((lo[u][2] - m) * LOG2E);
        float e3 = exp2f((lo[u][3] - m) * LOG2E);
        lo[u][0] = e0; lo[u][1] = e1; lo[u][2] = e2; lo[u][3] = e3;
        float s4 = (e0 + e1) + (e2 + e3);
        #pragma unroll
        for (int s = 1; s < 64; s <<= 1)
            s4 += __shfl_xor(s4, s, 64);
        sum[u] = s4;
    }
    #pragma unroll
    for (int u = 0; u < 4; ++u) {
        int r = ig * 4 + u;
        *(float2*)(sL + r * 260 + 2 * jg)       = make_float2(lo[u][0], lo[u][1]);
        *(float2*)(sL + r * 260 + 128 + 2 * jg) = make_float2(lo[u][2], lo[u][3]);
    }
    __syncthreads();  // all phase-1 LDS reads done; sL visible

    // stage V [j][d] into reused region
    #pragma unroll
    for (int u = 0; u < 8; ++u) {
        int j = (tid >> 3) + u * 32;
        int d4 = (tid & 7) * 4;
        *(float4*)(sV + j * 32 + d4) =
            *(const float4*)(V + ((size_t)(b * Lc + j) * DMc + h * DHc + d4));
    }
    __syncthreads();

    // PV: thread = (row pi, d-pair dg)
    int pi = tid >> 4;
    int dg = tid & 15;
    int uu = (tid >> 4) & 3;
    float srow = (uu == 0) ? sum[0] : (uu == 1) ? sum[1] : (uu == 2) ? sum[2] : sum[3];
    float rs = 1.0f / srow;
    float o0 = 0.f, o1 = 0.f;
    #pragma unroll 4
    for (int j4 = 0; j4 < 256; j4 += 4) {
        float4 p4 = *(const float4*)(sL + pi * 260 + j4);
        float2 v0 = *(const float2*)(sV + (j4 + 0) * 32 + dg * 2);
        float2 v1 = *(const float2*)(sV + (j4 + 1) * 32 + dg * 2);
        float2 v2 = *(const float2*)(sV + (j4 + 2) * 32 + dg * 2);
        float2 v3 = *(const float2*)(sV + (j4 + 3) * 32 + dg * 2);
        o0 += p4.x * v0.x + p4.y * v1.x + p4.z * v2.x + p4.w * v3.x;
        o1 += p4.x * v0.y + p4.y * v1.y + p4.z * v2.y + p4.w * v3.y;
    }
    *(float2*)(attn_out + (size_t)(b * Lc + i0 + pi) * DMc + h * DHc + dg * 2) =
        make_float2(o0 * rs, o1 * rs);
}

// ---------------------------------------------------------------------------
extern "C" void kernel_launch(void* const* d_in, const int* in_sizes, int n_in,
                              void* d_out, int out_size, void* d_ws, size_t ws_size,
                              hipStream_t stream) {
    (void)in_sizes; (void)n_in; (void)out_size; (void)ws_size;
    const float* x      = (const float*)d_in[0];
    const float* t      = (const float*)d_in[1];
    const float* WQ     = (const float*)d_in[2];
    const float* WK     = (const float*)d_in[3];
    const float* WV     = (const float*)d_in[4];
    const float* WO     = (const float*)d_in[5];
    const float* bO     = (const float*)d_in[6];
    const float* mu_abs = (const float*)d_in[7];
    const float* sg_abs = (const float*)d_in[8];
    const float* w_abs  = (const float*)d_in[9];
    const float* mu_rel = (const float*)d_in[10];
    const float* sg_rel = (const float*)d_in[11];
    const float* w_rel  = (const float*)d_in[12];
    const float* alpha  = (const float*)d_in[13];
    const float* beta   = (const float*)d_in[14];
    const float* gamma  = (const float*)d_in[15];
    float* out = (float*)d_out;
    float* ws = (float*)d_ws;

    float* Qb = ws;                       // 131072
    float* Kb = ws + 131072;              // 131072
    float* Vb = ws + 262144;              // 131072
    float* AO = ws + 393216;              // 131072
    float* GA = ws + 524288;              // 4096
    float4* PABS = (float4*)(ws + 528384);  // 16384 floats
    float4* PREL = (float4*)(ws + 544768);  // 16384 floats
    float* GR = ws + 561152;              // 1048576

    k_pack<<<dim3(16), dim3(256), 0, stream>>>(mu_abs, sg_abs, w_abs, PABS);
    k_pack<<<dim3(16), dim3(256), 0, stream>>>(mu_rel, sg_rel, w_rel, PREL);
    k_gabs<<<dim3(Bc * Hc, 4), dim3(256), 0, stream>>>(t, PABS, GA);
    k_grel<<<dim3(136, Bc, 2), dim3(256), 0, stream>>>(t, PREL, GR);
    k_gemm_nt<32, 64, 2, 4><<<dim3(16, 4, 3), dim3(256), 0, stream>>>(
        x, WQ, WK, WV, Qb, Kb, Vb, nullptr, Bc * Lc, DMc, DMc);
    k_attn<<<dim3(Lc / 16, Hc, Bc), dim3(256), 0, stream>>>(
        Qb, Kb, Vb, x, GA, GR, alpha, beta, gamma, AO);
    k_gemm_nt<32, 32, 2, 2><<<dim3(16, 8, 1), dim3(256), 0, stream>>>(
        AO, WO, WO, WO, out, out, out, bO, Bc * Lc, DMc, DMc);
}

// Round 3
// 180.686 us; speedup vs baseline: 1.4256x; 1.4256x over previous
//
#include <hip/hip_runtime.h>
#include <math.h>

constexpr int Bc = 2, Lc = 256, DMc = 256, Hc = 8, NKc = 4, Tc = 4, DHc = 32;
constexpr float LOG2E = 1.4426950408889634f;
constexpr float RSQRT_DH = 0.17677669529663687f; // 1/sqrt(32)
#define EXP2 __builtin_amdgcn_exp2f

// ---------------------------------------------------------------------------
// Pack gaussian params: out[h*512 + t*128 + d*4 + k] = {s, -mu*s, w/32, 0}
// with s = sqrt(log2e/2)/sigma, so that
//   w*exp(-(tau-mu)^2/(2 sg^2)) == w * exp2(-(fma(tau,s,-mu*s))^2)
// grid (16, 2): y=0 -> abs params, y=1 -> rel params.
// ---------------------------------------------------------------------------
__global__ void k_pack(const float* __restrict__ mu_a, const float* __restrict__ sg_a,
                       const float* __restrict__ w_a,
                       const float* __restrict__ mu_r, const float* __restrict__ sg_r,
                       const float* __restrict__ w_r,
                       float4* __restrict__ out_a, float4* __restrict__ out_r) {
    int p = blockIdx.x * 256 + threadIdx.x;  // [0, 4096)
    const float* mu = blockIdx.y ? mu_r : mu_a;
    const float* sg = blockIdx.y ? sg_r : sg_a;
    const float* w  = blockIdx.y ? w_r  : w_a;
    float4* out     = blockIdx.y ? out_r : out_a;
    int h = p >> 9, r = p & 511, t = r >> 7, dk = r & 127;
    int d = dk >> 2, k = dk & 3;
    int src = ((h * DHc + d) * Tc + t) * NKc + k;
    float s = sqrtf(0.5f * LOG2E) / sg[src];
    out[p] = make_float4(s, -mu[src] * s, w[src] * (1.0f / 32.0f), 0.0f);
}

// ---------------------------------------------------------------------------
// g_abs[b,h,i]: grid (B*H, 4), block 256 = 64 i-lanes x 4 t-groups.
// ---------------------------------------------------------------------------
__global__ void k_gabs(const float* __restrict__ tarr, const float4* __restrict__ pabs,
                       float* __restrict__ gabs) {
    int b = blockIdx.x / Hc, h = blockIdx.x % Hc;
    int lane = threadIdx.x & 63;
    int tg = threadIdx.x >> 6;
    int i = blockIdx.y * 64 + lane;
    float tv = tarr[(b * Lc + i) * Tc + tg];
    const float4* pp = pabs + (h * Tc + tg) * 128;
    float a0 = 0.f, a1 = 0.f;
    #pragma unroll 4
    for (int m = 0; m < 128; m += 2) {
        float4 q0 = pp[m], q1 = pp[m + 1];
        float d0 = fmaf(tv, q0.x, q0.y); a0 = fmaf(q0.z, EXP2(-(d0 * d0)), a0);
        float d1 = fmaf(tv, q1.x, q1.y); a1 = fmaf(q1.z, EXP2(-(d1 * d1)), a1);
    }
    __shared__ float red[4][64];
    red[tg][lane] = a0 + a1;
    __syncthreads();
    if (threadIdx.x < 64)
        gabs[(b * Hc + h) * Lc + i] = red[0][lane] + red[1][lane] + red[2][lane] + red[3][lane];
}

// ---------------------------------------------------------------------------
// g_rel[b,h,i,j]: symmetric 16x16 tile pairs, h in grid.z.
// grid (136, B, H) = 2176 blocks. Per eval: fma, mul, exp2(-e), fma.
// ---------------------------------------------------------------------------
__global__ void __launch_bounds__(256) k_grel(const float* __restrict__ tarr,
                                              const float4* __restrict__ prel,
                                              float* __restrict__ grel) {
    int p = blockIdx.x, b = blockIdx.y, h = blockIdx.z;
    int ti = 0;
    for (;; ++ti) { int cnt = 16 - ti; if (p < cnt) break; p -= cnt; }
    int tj = ti + p;
    int di = threadIdx.x >> 4, dj = threadIdx.x & 15;
    int i = ti * 16 + di, j = tj * 16 + dj;
    float4 t_i = *(const float4*)(tarr + (b * Lc + i) * Tc);
    float4 t_j = *(const float4*)(tarr + (b * Lc + j) * Tc);
    float tr0 = fabsf(t_i.x - t_j.x), tr1 = fabsf(t_i.y - t_j.y);
    float tr2 = fabsf(t_i.z - t_j.z), tr3 = fabsf(t_i.w - t_j.w);
    const float4* pp = prel + h * 512;
    float a0 = 0.f, a1 = 0.f, a2 = 0.f, a3 = 0.f;
    #pragma unroll 4
    for (int m = 0; m < 128; ++m) {
        float4 q0 = pp[m];
        float4 q1 = pp[128 + m];
        float4 q2 = pp[256 + m];
        float4 q3 = pp[384 + m];
        float d0 = fmaf(tr0, q0.x, q0.y); a0 = fmaf(q0.z, EXP2(-(d0 * d0)), a0);
        float d1 = fmaf(tr1, q1.x, q1.y); a1 = fmaf(q1.z, EXP2(-(d1 * d1)), a1);
        float d2 = fmaf(tr2, q2.x, q2.y); a2 = fmaf(q2.z, EXP2(-(d2 * d2)), a2);
        float d3 = fmaf(tr3, q3.x, q3.y); a3 = fmaf(q3.z, EXP2(-(d3 * d3)), a3);
    }
    float g = (a0 + a1) + (a2 + a3);
    float* gb = grel + (size_t)(b * Hc + h) * (Lc * Lc);
    gb[i * Lc + j] = g;
    if (ti != tj) {
        __shared__ float lt[16][17];
        lt[di][dj] = g;
        __syncthreads();
        gb[(tj * 16 + di) * Lc + (ti * 16 + dj)] = lt[dj][di];
    }
}

// ---------------------------------------------------------------------------
// fp32 GEMM  C[M,N] = scale * A[M,K] @ W[N,K]^T (+bias). LDS [k][m], pitch+1.
// blockIdx.z selects weight/output (fused QKV); scale0 applies to z==0 only.
// ---------------------------------------------------------------------------
template<int R, int PER>
__device__ __forceinline__ void stage_tile(const float* __restrict__ src, int ld,
                                           int row0, int k0, float* __restrict__ dst, int tid) {
    int row = tid / (16 / PER);
    int cb = (tid % (16 / PER)) * PER;
    const float* g = src + (size_t)(row0 + row) * ld + k0 + cb;
    float v[PER];
    #pragma unroll
    for (int u = 0; u < PER; ++u) v[u] = g[u];
    #pragma unroll
    for (int u = 0; u < PER; ++u) dst[(cb + u) * (R + 1) + row] = v[u];
}

template<int BM, int BN, int TM, int TN>
__global__ void __launch_bounds__(256) k_gemm_nt(
    const float* __restrict__ A,
    const float* __restrict__ W0, const float* __restrict__ W1, const float* __restrict__ W2,
    float* __restrict__ C0, float* __restrict__ C1, float* __restrict__ C2,
    const float* __restrict__ bias, float scale0, int M, int N, int K)
{
    const float* W = (blockIdx.z == 0) ? W0 : (blockIdx.z == 1 ? W1 : W2);
    float* C = (blockIdx.z == 0) ? C0 : (blockIdx.z == 1 ? C1 : C2);
    float sc = (blockIdx.z == 0) ? scale0 : 1.0f;
    __shared__ float As[16 * (BM + 1)];
    __shared__ float Ws[16 * (BN + 1)];
    int tid = threadIdx.x;
    int tx = tid % (BN / TN);
    int ty = tid / (BN / TN);
    int m0 = blockIdx.x * BM, n0 = blockIdx.y * BN;
    float acc[TM][TN] = {};
    for (int k0 = 0; k0 < K; k0 += 16) {
        stage_tile<BM, BM * 16 / 256>(A, K, m0, k0, As, tid);
        stage_tile<BN, BN * 16 / 256>(W, K, n0, k0, Ws, tid);
        __syncthreads();
        #pragma unroll
        for (int k = 0; k < 16; ++k) {
            float a[TM], w[TN];
            #pragma unroll
            for (int u = 0; u < TM; ++u) a[u] = As[k * (BM + 1) + ty * TM + u];
            #pragma unroll
            for (int v = 0; v < TN; ++v) w[v] = Ws[k * (BN + 1) + tx * TN + v];
            #pragma unroll
            for (int u = 0; u < TM; ++u)
                #pragma unroll
                for (int v = 0; v < TN; ++v)
                    acc[u][v] = fmaf(a[u], w[v], acc[u][v]);
        }
        __syncthreads();
    }
    #pragma unroll
    for (int u = 0; u < TM; ++u) {
        int m = m0 + ty * TM + u;
        #pragma unroll
        for (int v = 0; v < TN; ++v) {
            float o = acc[u][v] * sc;
            if (bias) o += bias[n0 + tx * TN + v];
            C[(size_t)m * N + n0 + tx * TN + v] = o;
        }
    }
}

// ---------------------------------------------------------------------------
// S = Q@K^T (Q pre-scaled by 1/sqrt(dh)), P = X@X^T per (b,h); 64x64 tiles,
// K-dim = 32. Fused modulation: logit = S*(P*(2*alpha*g_abs + beta*g_rel)+gamma)
// written IN-PLACE over the g_rel buffer. grid (4,4,16).
// ---------------------------------------------------------------------------
__global__ void __launch_bounds__(256) k_sp(
    const float* __restrict__ Q, const float* __restrict__ K, const float* __restrict__ x,
    const float* __restrict__ gabs,
    const float* __restrict__ alpha, const float* __restrict__ beta, const float* __restrict__ gamma,
    float* __restrict__ G)   // in: g_rel, out: logits
{
    constexpr int PITCH = 68;  // multiple of 4 (b128-aligned rows), 68%32=4
    int it = blockIdx.x, jt = blockIdx.y, bh = blockIdx.z;
    int b = bh >> 3, h = bh & 7;
    int i0 = it * 64, j0 = jt * 64;
    int tid = threadIdx.x;
    __shared__ float sm[4 * 32 * PITCH];
    float* sQ  = sm;
    float* sK  = sm + 32 * PITCH;
    float* sXi = sm + 64 * PITCH;
    float* sXj = sm + 96 * PITCH;

    int r0 = tid >> 3;           // 0..31
    int c4 = (tid & 7) * 4;      // 0,4,..,28
    #pragma unroll
    for (int uu = 0; uu < 2; ++uu) {
        int r = r0 + uu * 32;
        float4 qv = *(const float4*)(Q + ((size_t)(b * Lc + i0 + r) * DMc + h * DHc + c4));
        float4 kv = *(const float4*)(K + ((size_t)(b * Lc + j0 + r) * DMc + h * DHc + c4));
        float4 xi = *(const float4*)(x + ((size_t)(b * Lc + i0 + r) * DMc + h * DHc + c4));
        float4 xj = *(const float4*)(x + ((size_t)(b * Lc + j0 + r) * DMc + h * DHc + c4));
        const float* q_ = (const float*)&qv; const float* k_ = (const float*)&kv;
        const float* a_ = (const float*)&xi; const float* c_ = (const float*)&xj;
        #pragma unroll
        for (int u = 0; u < 4; ++u) {
            sQ [(c4 + u) * PITCH + r] = q_[u];
            sK [(c4 + u) * PITCH + r] = k_[u];
            sXi[(c4 + u) * PITCH + r] = a_[u];
            sXj[(c4 + u) * PITCH + r] = c_[u];
        }
    }
    __syncthreads();

    int tx = tid & 15, ty = tid >> 4;
    int i4 = ty * 4, j4 = tx * 4;
    float accS[4][4] = {}, accP[4][4] = {};
    #pragma unroll 4
    for (int k = 0; k < 32; ++k) {
        float4 qa = *(const float4*)(sQ  + k * PITCH + i4);
        float4 kb = *(const float4*)(sK  + k * PITCH + j4);
        float4 xa = *(const float4*)(sXi + k * PITCH + i4);
        float4 xb = *(const float4*)(sXj + k * PITCH + j4);
        const float* qa_ = (const float*)&qa; const float* kb_ = (const float*)&kb;
        const float* xa_ = (const float*)&xa; const float* xb_ = (const float*)&xb;
        #pragma unroll
        for (int u = 0; u < 4; ++u)
            #pragma unroll
            for (int v = 0; v < 4; ++v) {
                accS[u][v] = fmaf(qa_[u], kb_[v], accS[u][v]);
                accP[u][v] = fmaf(xa_[u], xb_[v], accP[u][v]);
            }
    }

    float la = alpha[h], lb = beta[h], lg = gamma[h];
    float* gb = G + (size_t)bh * (Lc * Lc);
    #pragma unroll
    for (int u = 0; u < 4; ++u) {
        int i = i0 + i4 + u;
        float gi2 = 2.0f * la * gabs[bh * Lc + i];
        float* addr = gb + (size_t)i * Lc + j0 + j4;
        float4 gr = *(const float4*)addr;
        float4 o;
        o.x = accS[u][0] * fmaf(accP[u][0], fmaf(lb, gr.x, gi2), lg);
        o.y = accS[u][1] * fmaf(accP[u][1], fmaf(lb, gr.y, gi2), lg);
        o.z = accS[u][2] * fmaf(accP[u][2], fmaf(lb, gr.z, gi2), lg);
        o.w = accS[u][3] * fmaf(accP[u][3], fmaf(lb, gr.w, gi2), lg);
        *(float4*)addr = o;
    }
}

// ---------------------------------------------------------------------------
// Row softmax, in place. One wave per row; grid 1024, block 256.
// ---------------------------------------------------------------------------
__global__ void __launch_bounds__(256) k_softmax(float* __restrict__ L) {
    int row = blockIdx.x * 4 + (threadIdx.x >> 6);
    int lane = threadIdx.x & 63;
    float* p = L + (size_t)row * Lc + lane * 4;
    float4 v = *(float4*)p;
    float m = fmaxf(fmaxf(v.x, v.y), fmaxf(v.z, v.w));
    #pragma unroll
    for (int s = 1; s < 64; s <<= 1) m = fmaxf(m, __shfl_xor(m, s, 64));
    v.x = EXP2((v.x - m) * LOG2E);
    v.y = EXP2((v.y - m) * LOG2E);
    v.z = EXP2((v.z - m) * LOG2E);
    v.w = EXP2((v.w - m) * LOG2E);
    float s4 = (v.x + v.y) + (v.z + v.w);
    #pragma unroll
    for (int s = 1; s < 64; s <<= 1) s4 += __shfl_xor(s4, s, 64);
    float rs = 1.0f / s4;
    v.x *= rs; v.y *= rs; v.z *= rs; v.w *= rs;
    *(float4*)p = v;
}

// ---------------------------------------------------------------------------
// PV: attn_out[b,i,h*32+d] = sum_j probs[bh,i,j] * V[b,j,h*32+d].
// grid (16 i-tiles, 16 bh), block 256: thread = (i = tid>>4, d2 = (tid&15)*2).
// ---------------------------------------------------------------------------
__global__ void __launch_bounds__(256) k_pv(const float* __restrict__ P,
                                            const float* __restrict__ V,
                                            float* __restrict__ AO) {
    int it = blockIdx.x, bh = blockIdx.y;
    int b = bh >> 3, h = bh & 7;
    int i0 = it * 16;
    int tid = threadIdx.x;
    __shared__ float sV[64 * 32];
    __shared__ float sP[16 * 68];
    int i = tid >> 4;
    int d2 = (tid & 15) * 2;
    float ax = 0.f, ay = 0.f;
    const float* Pb = P + (size_t)bh * (Lc * Lc);
    for (int c = 0; c < 4; ++c) {
        int j0 = c * 64;
        int jj = tid >> 3, c4 = (tid & 7) * 4;
        #pragma unroll
        for (int uu = 0; uu < 2; ++uu) {
            int r = jj + uu * 32;
            *(float4*)(sV + r * 32 + c4) =
                *(const float4*)(V + ((size_t)(b * Lc + j0 + r) * DMc + h * DHc + c4));
        }
        int pr = tid >> 4, pc4 = (tid & 15) * 4;
        *(float4*)(sP + pr * 68 + pc4) =
            *(const float4*)(Pb + (size_t)(i0 + pr) * Lc + j0 + pc4);
        __syncthreads();
        #pragma unroll 8
        for (int q = 0; q < 64; ++q) {
            float pv = sP[i * 68 + q];
            float2 vv = *(const float2*)(sV + q * 32 + d2);
            ax = fmaf(pv, vv.x, ax);
            ay = fmaf(pv, vv.y, ay);
        }
        __syncthreads();
    }
    *(float2*)(AO + ((size_t)(b * Lc + i0 + i) * DMc + h * DHc + d2)) = make_float2(ax, ay);
}

// ---------------------------------------------------------------------------
extern "C" void kernel_launch(void* const* d_in, const int* in_sizes, int n_in,
                              void* d_out, int out_size, void* d_ws, size_t ws_size,
                              hipStream_t stream) {
    (void)in_sizes; (void)n_in; (void)out_size; (void)ws_size;
    const float* x      = (const float*)d_in[0];
    const float* t      = (const float*)d_in[1];
    const float* WQ     = (const float*)d_in[2];
    const float* WK     = (const float*)d_in[3];
    const float* WV     = (const float*)d_in[4];
    const float* WO     = (const float*)d_in[5];
    const float* bO     = (const float*)d_in[6];
    const float* mu_abs = (const float*)d_in[7];
    const float* sg_abs = (const float*)d_in[8];
    const float* w_abs  = (const float*)d_in[9];
    const float* mu_rel = (const float*)d_in[10];
    const float* sg_rel = (const float*)d_in[11];
    const float* w_rel  = (const float*)d_in[12];
    const float* alpha  = (const float*)d_in[13];
    const float* beta   = (const float*)d_in[14];
    const float* gamma  = (const float*)d_in[15];
    float* out = (float*)d_out;
    float* ws = (float*)d_ws;

    // Workspace layout (floats). NOTE: PABS/PREL are 4096 float4 = 16384
    // floats EACH — R2 spaced them 8192 apart (overlap => corruption).
    float* Qb = ws;                          // 131072
    float* Kb = ws + 131072;                 // 131072
    float* Vb = ws + 262144;                 // 131072
    float* AO = ws + 393216;                 // 131072
    float* GA = ws + 524288;                 // 4096
    float4* PABS = (float4*)(ws + 528384);   // 16384 floats
    float4* PREL = (float4*)(ws + 544768);   // 16384 floats
    float* GR = ws + 561152;                 // 1048576 (g_rel -> logits -> probs)

    k_pack<<<dim3(16, 2), dim3(256), 0, stream>>>(mu_abs, sg_abs, w_abs,
                                                  mu_rel, sg_rel, w_rel, PABS, PREL);
    k_gabs<<<dim3(Bc * Hc, 4), dim3(256), 0, stream>>>(t, PABS, GA);
    k_grel<<<dim3(136, Bc, Hc), dim3(256), 0, stream>>>(t, PREL, GR);
    k_gemm_nt<32, 32, 2, 2><<<dim3(16, 8, 3), dim3(256), 0, stream>>>(
        x, WQ, WK, WV, Qb, Kb, Vb, nullptr, RSQRT_DH, Bc * Lc, DMc, DMc);
    k_sp<<<dim3(4, 4, 16), dim3(256), 0, stream>>>(Qb, Kb, x, GA, alpha, beta, gamma, GR);
    k_softmax<<<dim3(1024), dim3(256), 0, stream>>>(GR);
    k_pv<<<dim3(16, 16), dim3(256), 0, stream>>>(GR, Vb, AO);
    k_gemm_nt<32, 32, 2, 2><<<dim3(16, 8, 1), dim3(256), 0, stream>>>(
        AO, WO, WO, WO, out, out, out, bO, 1.0f, Bc * Lc, DMc, DMc);
}

// Round 4
// 159.325 us; speedup vs baseline: 1.6167x; 1.1341x over previous
//
#include <hip/hip_runtime.h>
#include <math.h>

constexpr int Bc = 2, Lc = 256, DMc = 256, Hc = 8, DHc = 32;
constexpr float LOG2E = 1.4426950408889634f;
constexpr float RSQRT_DH = 0.17677669529663687f; // 1/sqrt(32)
#define EXP2 __builtin_amdgcn_exp2f

// ===========================================================================
// kA: fused independent-pre-work kernel. Block roles by blockIdx.x range:
//   [0,2176)    g_rel   (136 sym tile-pairs x B x H)
//   [2176,2240) g_abs   (2b x 4 i-quarters x 8h)
//   [2240,2624) QKV gemm (3z x 16m x 8n tiles of 32x32)
// grel/gabs per-eval: v_sub, v_mul, v_mul, v_exp, v_fma — mu/w via s_load
// (wave-uniform, <=1 SGPR per VALU op), -log2e/(2*sg^2) via LDS b128.
// ===========================================================================

__device__ __forceinline__ void role_grel(int idx, const float* __restrict__ t,
                                          const float* __restrict__ mu, const float* __restrict__ sg,
                                          const float* __restrict__ w, float* __restrict__ grel,
                                          float* smem) {
    int h = idx & 7, b = (idx >> 3) & 1, p = idx >> 4;
    int tid = threadIdx.x;
    {   // ns2[512] = -log2e/(2*sigma^2), layout d*16 + tg*4 + k (same as inputs)
        float2 s2 = *(const float2*)(sg + h * 512 + tid * 2);
        float2 o;
        o.x = -(0.5f * LOG2E) / (s2.x * s2.x);
        o.y = -(0.5f * LOG2E) / (s2.y * s2.y);
        *(float2*)(smem + tid * 2) = o;
    }
    __syncthreads();
    int ti = 0;
    for (;; ++ti) { int c = 16 - ti; if (p < c) break; p -= c; }
    int tj = ti + p;
    int di = tid >> 4, dj = tid & 15;
    int i = ti * 16 + di, j = tj * 16 + dj;
    float4 t_i = *(const float4*)(t + (b * Lc + i) * 4);
    float4 t_j = *(const float4*)(t + (b * Lc + j) * 4);
    float tr[4] = {fabsf(t_i.x - t_j.x), fabsf(t_i.y - t_j.y),
                   fabsf(t_i.z - t_j.z), fabsf(t_i.w - t_j.w)};
    float g = 0.f;
    #pragma unroll
    for (int tg = 0; tg < 4; ++tg) {
        const float* muB = mu + h * 512 + tg * 4;
        const float* wB  = w  + h * 512 + tg * 4;
        const float* nsB = smem + tg * 4;
        float tv = tr[tg];
        float acc = 0.f;
        #pragma unroll 4
        for (int d = 0; d < 32; ++d) {
            float4 m4 = *(const float4*)(muB + d * 16);   // s_load_dwordx4
            float4 w4 = *(const float4*)(wB  + d * 16);   // s_load_dwordx4
            float4 n4 = *(const float4*)(nsB + d * 16);   // ds_read_b128
            float d0 = tv - m4.x; acc = fmaf(w4.x, EXP2(d0 * d0 * n4.x), acc);
            float d1 = tv - m4.y; acc = fmaf(w4.y, EXP2(d1 * d1 * n4.y), acc);
            float d2 = tv - m4.z; acc = fmaf(w4.z, EXP2(d2 * d2 * n4.z), acc);
            float d3 = tv - m4.w; acc = fmaf(w4.w, EXP2(d3 * d3 * n4.w), acc);
        }
        g += acc;
    }
    g *= (1.0f / 32.0f);
    float* gb = grel + (size_t)(b * Hc + h) * (Lc * Lc);
    gb[i * Lc + j] = g;
    if (ti != tj) {
        float* lt = smem + 512;   // 16x17
        lt[di * 17 + dj] = g;
        __syncthreads();
        gb[(tj * 16 + di) * Lc + (ti * 16 + dj)] = lt[dj * 17 + di];
    }
}

__device__ __forceinline__ void role_gabs(int idx, const float* __restrict__ t,
                                          const float* __restrict__ mu, const float* __restrict__ sg,
                                          const float* __restrict__ w, float* __restrict__ gabs,
                                          float* smem) {
    int h = idx & 7, b = (idx >> 3) & 1, q = idx >> 4;   // q: i-quarter
    int tid = threadIdx.x;
    {
        float2 s2 = *(const float2*)(sg + h * 512 + tid * 2);
        float2 o;
        o.x = -(0.5f * LOG2E) / (s2.x * s2.x);
        o.y = -(0.5f * LOG2E) / (s2.y * s2.y);
        *(float2*)(smem + tid * 2) = o;
    }
    __syncthreads();
    int lane = tid & 63, tg = tid >> 6;
    int i = q * 64 + lane;
    float tv = t[(b * Lc + i) * 4 + tg];
    const float* muB = mu + h * 512 + tg * 4;
    const float* wB  = w  + h * 512 + tg * 4;
    const float* nsB = smem + tg * 4;
    float acc = 0.f;
    #pragma unroll 4
    for (int d = 0; d < 32; ++d) {
        float4 m4 = *(const float4*)(muB + d * 16);
        float4 w4 = *(const float4*)(wB  + d * 16);
        float4 n4 = *(const float4*)(nsB + d * 16);
        float d0 = tv - m4.x; acc = fmaf(w4.x, EXP2(d0 * d0 * n4.x), acc);
        float d1 = tv - m4.y; acc = fmaf(w4.y, EXP2(d1 * d1 * n4.y), acc);
        float d2 = tv - m4.z; acc = fmaf(w4.z, EXP2(d2 * d2 * n4.z), acc);
        float d3 = tv - m4.w; acc = fmaf(w4.w, EXP2(d3 * d3 * n4.w), acc);
    }
    float* red = smem + 512;   // 4 x 64
    red[tg * 64 + lane] = acc;
    __syncthreads();
    if (tid < 64)
        gabs[(b * Hc + h) * Lc + q * 64 + lane] =
            (red[lane] + red[64 + lane] + red[128 + lane] + red[192 + lane]) * (1.0f / 32.0f);
}

template<int R, int PER>
__device__ __forceinline__ void stage_tile(const float* __restrict__ src, int ld,
                                           int row0, int k0, float* __restrict__ dst, int tid) {
    int row = tid / (16 / PER);
    int cb = (tid % (16 / PER)) * PER;
    const float* g = src + (size_t)(row0 + row) * ld + k0 + cb;
    float v[PER];
    #pragma unroll
    for (int u = 0; u < PER; ++u) v[u] = g[u];
    #pragma unroll
    for (int u = 0; u < PER; ++u) dst[(cb + u) * (R + 1) + row] = v[u];
}

__device__ __forceinline__ void gemm32(const float* __restrict__ A, const float* __restrict__ W,
                                       float* __restrict__ C, const float* __restrict__ bias,
                                       float sc, int m0, int n0, float* smem) {
    // C[m0:+32, n0:+32] = sc * A[.,K=256] @ W^T (+bias); LDS [k][m] pitch 33.
    float* As = smem;
    float* Ws = smem + 16 * 33;
    int tid = threadIdx.x;
    int tx = tid & 15, ty = tid >> 4;
    float acc[2][2] = {};
    for (int k0 = 0; k0 < 256; k0 += 16) {
        stage_tile<32, 2>(A, 256, m0, k0, As, tid);
        stage_tile<32, 2>(W, 256, n0, k0, Ws, tid);
        __syncthreads();
        #pragma unroll
        for (int k = 0; k < 16; ++k) {
            float a0 = As[k * 33 + ty * 2], a1 = As[k * 33 + ty * 2 + 1];
            float w0 = Ws[k * 33 + tx * 2], w1 = Ws[k * 33 + tx * 2 + 1];
            acc[0][0] = fmaf(a0, w0, acc[0][0]);
            acc[0][1] = fmaf(a0, w1, acc[0][1]);
            acc[1][0] = fmaf(a1, w0, acc[1][0]);
            acc[1][1] = fmaf(a1, w1, acc[1][1]);
        }
        __syncthreads();
    }
    #pragma unroll
    for (int u = 0; u < 2; ++u) {
        int m = m0 + ty * 2 + u;
        #pragma unroll
        for (int v = 0; v < 2; ++v) {
            float o = acc[u][v] * sc;
            if (bias) o += bias[n0 + tx * 2 + v];
            C[(size_t)m * DMc + n0 + tx * 2 + v] = o;
        }
    }
}

__global__ void __launch_bounds__(256) kA(
    const float* __restrict__ x, const float* __restrict__ t,
    const float* __restrict__ WQ, const float* __restrict__ WK, const float* __restrict__ WV,
    const float* __restrict__ mu_a, const float* __restrict__ sg_a, const float* __restrict__ w_a,
    const float* __restrict__ mu_r, const float* __restrict__ sg_r, const float* __restrict__ w_r,
    float* __restrict__ Qb, float* __restrict__ Kb, float* __restrict__ Vb,
    float* __restrict__ GA, float* __restrict__ GR)
{
    __shared__ float smem[1056];   // max(gemm 2*16*33, grel 512+272, gabs 512+256)
    int bx = blockIdx.x;
    if (bx < 2176) {
        role_grel(bx, t, mu_r, sg_r, w_r, GR, smem);
    } else if (bx < 2240) {
        role_gabs(bx - 2176, t, mu_a, sg_a, w_a, GA, smem);
    } else {
        int idx = bx - 2240;          // 0..383
        int z = idx >> 7;             // 0:Q 1:K 2:V
        int r = idx & 127;
        int m0 = (r >> 3) * 32, n0 = (r & 7) * 32;
        const float* W = (z == 0) ? WQ : (z == 1) ? WK : WV;
        float* C = (z == 0) ? Qb : (z == 1) ? Kb : Vb;
        gemm32(x, W, C, nullptr, (z == 0) ? RSQRT_DH : 1.0f, m0, n0, smem);
    }
}

// ===========================================================================
// kB: S = Q@K^T (Q pre-scaled), P = X@X^T; 64x64 tiles, K=32. Fused
// modulation logit = S*(P*(2*alpha*g_abs + beta*g_rel)+gamma), in-place on GR.
// grid (4,4,16). [unchanged from R3 — proven]
// ===========================================================================
__global__ void __launch_bounds__(256) k_sp(
    const float* __restrict__ Q, const float* __restrict__ K, const float* __restrict__ x,
    const float* __restrict__ gabs,
    const float* __restrict__ alpha, const float* __restrict__ beta, const float* __restrict__ gamma,
    float* __restrict__ G)
{
    constexpr int PITCH = 68;
    int it = blockIdx.x, jt = blockIdx.y, bh = blockIdx.z;
    int b = bh >> 3, h = bh & 7;
    int i0 = it * 64, j0 = jt * 64;
    int tid = threadIdx.x;
    __shared__ float sm[4 * 32 * PITCH];
    float* sQ  = sm;
    float* sK  = sm + 32 * PITCH;
    float* sXi = sm + 64 * PITCH;
    float* sXj = sm + 96 * PITCH;

    int r0 = tid >> 3;
    int c4 = (tid & 7) * 4;
    #pragma unroll
    for (int uu = 0; uu < 2; ++uu) {
        int r = r0 + uu * 32;
        float4 qv = *(const float4*)(Q + ((size_t)(b * Lc + i0 + r) * DMc + h * DHc + c4));
        float4 kv = *(const float4*)(K + ((size_t)(b * Lc + j0 + r) * DMc + h * DHc + c4));
        float4 xi = *(const float4*)(x + ((size_t)(b * Lc + i0 + r) * DMc + h * DHc + c4));
        float4 xj = *(const float4*)(x + ((size_t)(b * Lc + j0 + r) * DMc + h * DHc + c4));
        const float* q_ = (const float*)&qv; const float* k_ = (const float*)&kv;
        const float* a_ = (const float*)&xi; const float* c_ = (const float*)&xj;
        #pragma unroll
        for (int u = 0; u < 4; ++u) {
            sQ [(c4 + u) * PITCH + r] = q_[u];
            sK [(c4 + u) * PITCH + r] = k_[u];
            sXi[(c4 + u) * PITCH + r] = a_[u];
            sXj[(c4 + u) * PITCH + r] = c_[u];
        }
    }
    __syncthreads();

    int tx = tid & 15, ty = tid >> 4;
    int i4 = ty * 4, j4 = tx * 4;
    float accS[4][4] = {}, accP[4][4] = {};
    #pragma unroll 4
    for (int k = 0; k < 32; ++k) {
        float4 qa = *(const float4*)(sQ  + k * PITCH + i4);
        float4 kb = *(const float4*)(sK  + k * PITCH + j4);
        float4 xa = *(const float4*)(sXi + k * PITCH + i4);
        float4 xb = *(const float4*)(sXj + k * PITCH + j4);
        const float* qa_ = (const float*)&qa; const float* kb_ = (const float*)&kb;
        const float* xa_ = (const float*)&xa; const float* xb_ = (const float*)&xb;
        #pragma unroll
        for (int u = 0; u < 4; ++u)
            #pragma unroll
            for (int v = 0; v < 4; ++v) {
                accS[u][v] = fmaf(qa_[u], kb_[v], accS[u][v]);
                accP[u][v] = fmaf(xa_[u], xb_[v], accP[u][v]);
            }
    }

    float la = alpha[h], lb = beta[h], lg = gamma[h];
    float* gb = G + (size_t)bh * (Lc * Lc);
    #pragma unroll
    for (int u = 0; u < 4; ++u) {
        int i = i0 + i4 + u;
        float gi2 = 2.0f * la * gabs[bh * Lc + i];
        float* addr = gb + (size_t)i * Lc + j0 + j4;
        float4 gr = *(const float4*)addr;
        float4 o;
        o.x = accS[u][0] * fmaf(accP[u][0], fmaf(lb, gr.x, gi2), lg);
        o.y = accS[u][1] * fmaf(accP[u][1], fmaf(lb, gr.y, gi2), lg);
        o.z = accS[u][2] * fmaf(accP[u][2], fmaf(lb, gr.z, gi2), lg);
        o.w = accS[u][3] * fmaf(accP[u][3], fmaf(lb, gr.w, gi2), lg);
        *(float4*)addr = o;
    }
}

// ===========================================================================
// kC: softmax fused into PV. grid (16 i-tiles, 16 bh), block 256.
// Pass1: thread (i=tid>>4, l=tid&15) loads 16 logits of row i, 16-lane
// shuffle max/sum, writes exp'd probs to sP. Pass2: PV from LDS; 1/sum
// applied in epilogue (uniform per row-group).
// ===========================================================================
__global__ void __launch_bounds__(256) k_pvsm(const float* __restrict__ P,
                                              const float* __restrict__ V,
                                              float* __restrict__ AO) {
    int it = blockIdx.x, bh = blockIdx.y;
    int b = bh >> 3, h = bh & 7;
    int i0 = it * 16;
    int tid = threadIdx.x;
    __shared__ float sP[16 * 260];
    __shared__ float sV[256 * 34];
    int i = tid >> 4, l = tid & 15;

    const float* row = P + (size_t)bh * (Lc * Lc) + (size_t)(i0 + i) * Lc + l * 16;
    float4 p0 = *(const float4*)(row);
    float4 p1 = *(const float4*)(row + 4);
    float4 p2 = *(const float4*)(row + 8);
    float4 p3 = *(const float4*)(row + 12);
    float m = fmaxf(fmaxf(fmaxf(p0.x, p0.y), fmaxf(p0.z, p0.w)),
                    fmaxf(fmaxf(p1.x, p1.y), fmaxf(p1.z, p1.w)));
    m = fmaxf(m, fmaxf(fmaxf(fmaxf(p2.x, p2.y), fmaxf(p2.z, p2.w)),
                       fmaxf(fmaxf(p3.x, p3.y), fmaxf(p3.z, p3.w))));
    #pragma unroll
    for (int s = 1; s < 16; s <<= 1) m = fmaxf(m, __shfl_xor(m, s, 64));
    float4 e0, e1, e2, e3;
    e0.x = EXP2((p0.x - m) * LOG2E); e0.y = EXP2((p0.y - m) * LOG2E);
    e0.z = EXP2((p0.z - m) * LOG2E); e0.w = EXP2((p0.w - m) * LOG2E);
    e1.x = EXP2((p1.x - m) * LOG2E); e1.y = EXP2((p1.y - m) * LOG2E);
    e1.z = EXP2((p1.z - m) * LOG2E); e1.w = EXP2((p1.w - m) * LOG2E);
    e2.x = EXP2((p2.x - m) * LOG2E); e2.y = EXP2((p2.y - m) * LOG2E);
    e2.z = EXP2((p2.z - m) * LOG2E); e2.w = EXP2((p2.w - m) * LOG2E);
    e3.x = EXP2((p3.x - m) * LOG2E); e3.y = EXP2((p3.y - m) * LOG2E);
    e3.z = EXP2((p3.z - m) * LOG2E); e3.w = EXP2((p3.w - m) * LOG2E);
    float sum = ((e0.x + e0.y) + (e0.z + e0.w)) + ((e1.x + e1.y) + (e1.z + e1.w)) +
                ((e2.x + e2.y) + (e2.z + e2.w)) + ((e3.x + e3.y) + (e3.z + e3.w));
    #pragma unroll
    for (int s = 1; s < 16; s <<= 1) sum += __shfl_xor(sum, s, 64);
    float rs = 1.0f / sum;
    *(float4*)(sP + i * 260 + l * 16)      = e0;
    *(float4*)(sP + i * 260 + l * 16 + 4)  = e1;
    *(float4*)(sP + i * 260 + l * 16 + 8)  = e2;
    *(float4*)(sP + i * 260 + l * 16 + 12) = e3;

    int jj = tid >> 3, c4 = (tid & 7) * 4;
    #pragma unroll
    for (int u = 0; u < 8; ++u) {
        int j = jj + u * 32;
        *(float4*)(sV + j * 34 + c4) =
            *(const float4*)(V + ((size_t)(b * Lc + j) * DMc + h * DHc + c4));
    }
    __syncthreads();

    int d2 = l * 2;
    float o0 = 0.f, o1 = 0.f;
    #pragma unroll 2
    for (int j4 = 0; j4 < 256; j4 += 4) {
        float4 p4 = *(const float4*)(sP + i * 260 + j4);
        float2 v0 = *(const float2*)(sV + (j4 + 0) * 34 + d2);
        float2 v1 = *(const float2*)(sV + (j4 + 1) * 34 + d2);
        float2 v2 = *(const float2*)(sV + (j4 + 2) * 34 + d2);
        float2 v3 = *(const float2*)(sV + (j4 + 3) * 34 + d2);
        o0 += p4.x * v0.x + p4.y * v1.x + p4.z * v2.x + p4.w * v3.x;
        o1 += p4.x * v0.y + p4.y * v1.y + p4.z * v2.y + p4.w * v3.y;
    }
    *(float2*)(AO + ((size_t)(b * Lc + i0 + i) * DMc + h * DHc + d2)) =
        make_float2(o0 * rs, o1 * rs);
}

// ===========================================================================
// kD: out = AO @ WO^T + bO.  grid (16,8), 32x32 tiles.
// ===========================================================================
__global__ void __launch_bounds__(256) k_out(const float* __restrict__ A,
                                             const float* __restrict__ W,
                                             const float* __restrict__ bias,
                                             float* __restrict__ C) {
    __shared__ float smem[2 * 16 * 33];
    gemm32(A, W, C, bias, 1.0f, blockIdx.x * 32, blockIdx.y * 32, smem);
}

// ===========================================================================
extern "C" void kernel_launch(void* const* d_in, const int* in_sizes, int n_in,
                              void* d_out, int out_size, void* d_ws, size_t ws_size,
                              hipStream_t stream) {
    (void)in_sizes; (void)n_in; (void)out_size; (void)ws_size;
    const float* x      = (const float*)d_in[0];
    const float* t      = (const float*)d_in[1];
    const float* WQ     = (const float*)d_in[2];
    const float* WK     = (const float*)d_in[3];
    const float* WV     = (const float*)d_in[4];
    const float* WO     = (const float*)d_in[5];
    const float* bO     = (const float*)d_in[6];
    const float* mu_abs = (const float*)d_in[7];
    const float* sg_abs = (const float*)d_in[8];
    const float* w_abs  = (const float*)d_in[9];
    const float* mu_rel = (const float*)d_in[10];
    const float* sg_rel = (const float*)d_in[11];
    const float* w_rel  = (const float*)d_in[12];
    const float* alpha  = (const float*)d_in[13];
    const float* beta   = (const float*)d_in[14];
    const float* gamma  = (const float*)d_in[15];
    float* out = (float*)d_out;
    float* ws = (float*)d_ws;

    float* Qb = ws;                // 131072 floats
    float* Kb = ws + 131072;
    float* Vb = ws + 262144;
    float* AO = ws + 393216;
    float* GA = ws + 524288;       // 4096
    float* GR = ws + 528384;       // 1048576 (g_rel -> logits)

    kA<<<dim3(2624), dim3(256), 0, stream>>>(x, t, WQ, WK, WV,
                                             mu_abs, sg_abs, w_abs,
                                             mu_rel, sg_rel, w_rel,
                                             Qb, Kb, Vb, GA, GR);
    k_sp<<<dim3(4, 4, 16), dim3(256), 0, stream>>>(Qb, Kb, x, GA, alpha, beta, gamma, GR);
    k_pvsm<<<dim3(16, 16), dim3(256), 0, stream>>>(GR, Vb, AO);
    k_out<<<dim3(16, 8), dim3(256), 0, stream>>>(AO, WO, bO, out);
}